// Round 1
// baseline (173.877 us; speedup 1.0000x reference)
//
#include <hip/hip_runtime.h>
#include <hip/hip_cooperative_groups.h>
#include <math.h>

#define UNITS 1024
#define FEAT  1024
#define GATES 4096   // 4*UNITS

// ---- fused single-kernel ws layout (float offsets) ----
#define FOFF_Z0   0            // z0 = b + x0@W            (4096 floats)
#define FOFF_Z1   GATES        // z1 = b + x1@W + h0@U     (4096 floats)
#define FOFF_FLAG (2 * GATES)  // int arrival counter (re-inited every launch)

// ---- legacy 3-kernel layout (fallback path only) ----
#define OFF_Z0  0
#define OFF_Z1X (GATES)
#define OFF_Z1L (2 * GATES)

__device__ __forceinline__ float sigmoidf(float x) { return 1.0f / (1.0f + expf(-x)); }

// XCD-aware swizzle: bx%8 = XCD heuristic, each XCD owns 32 consecutive
// 16-col groups = 512 contiguous columns.
__device__ __forceinline__ int col_group(int bx) {
    return ((bx & 7) << 5) + (bx >> 3);
}

// ============================================================================
// Fused cooperative kernel: 256 blocks x 256 threads, 1 block/CU.
// Phase 1: z0 = b + x0@W, z1x = b + x1@W (z1x kept in LDS);
//          U tile prefetched to registers CONCURRENTLY with the W read.
// grid.sync()
// Phase 2: every block computes full h0/c0 (1024) from z0 into LDS.
// Phase 3: z1 = z1x + h0@U from the register-held U tile; write z1.
// Last-arriving block: step-1 gates + tanh + dense(2) + finite-diff outputs.
// ============================================================================
__global__ __launch_bounds__(256, 1) void k_fused(
        const float* __restrict__ x,
        const float* __restrict__ W,
        const float* __restrict__ U,
        const float* __restrict__ b,
        const float* __restrict__ f,
        const float* __restrict__ Wd,
        const float* __restrict__ bd,
        float* __restrict__ ws,
        float* __restrict__ out) {
    int tid = threadIdx.x;
    int c0 = col_group(blockIdx.x) * 16;

    __shared__ float xs0[FEAT], xs1[FEAT];
    __shared__ float h0s[UNITS], c0s[UNITS];
    __shared__ float z1xs[16];
    __shared__ float4 pr0[4][4], pr1[4][4];
    __shared__ float4 wred[4];
    __shared__ int lastflag;

    // Re-init the arrival counter every launch (ws is poisoned between runs).
    // Happens-before all arrivals via the grid.sync below.
    if (blockIdx.x == 0 && tid == 0) {
        __hip_atomic_store((int*)&ws[FOFF_FLAG], 0, __ATOMIC_RELAXED,
                           __HIP_MEMORY_SCOPE_AGENT);
    }

    {
        float4 v0 = *reinterpret_cast<const float4*>(&x[tid * 4]);
        float4 v1 = *reinterpret_cast<const float4*>(&x[FEAT + tid * 4]);
        *reinterpret_cast<float4*>(&xs0[tid * 4]) = v0;
        *reinterpret_cast<float4*>(&xs1[tid * 4]) = v1;
    }
    __syncthreads();

    int q = tid & 3;
    int rowbase = tid >> 2;               // 0..63
    const float* wp = W + (size_t)rowbase * GATES + c0 + q * 4;
    const float* up = U + (size_t)rowbase * GATES + c0 + q * 4;

    // U tile prefetch into registers — streams from HBM concurrently with W.
    float4 ureg[16];
#pragma unroll
    for (int it = 0; it < 16; ++it)
        ureg[it] = *reinterpret_cast<const float4*>(up + (size_t)it * 64 * GATES);

    // ---- Phase 1: x0@W and x1@W ----
    float4 a0 = make_float4(0.f, 0.f, 0.f, 0.f);
    float4 a1 = make_float4(0.f, 0.f, 0.f, 0.f);
#pragma unroll
    for (int it = 0; it < 16; ++it) {
        int row = it * 64 + rowbase;
        float4 wv = *reinterpret_cast<const float4*>(wp + (size_t)it * 64 * GATES);
        float x0v = xs0[row], x1v = xs1[row];
        a0.x += x0v * wv.x; a0.y += x0v * wv.y; a0.z += x0v * wv.z; a0.w += x0v * wv.w;
        a1.x += x1v * wv.x; a1.y += x1v * wv.y; a1.z += x1v * wv.z; a1.w += x1v * wv.w;
    }
#pragma unroll
    for (int s = 32; s >= 4; s >>= 1) {
        a0.x += __shfl_down(a0.x, s); a0.y += __shfl_down(a0.y, s);
        a0.z += __shfl_down(a0.z, s); a0.w += __shfl_down(a0.w, s);
        a1.x += __shfl_down(a1.x, s); a1.y += __shfl_down(a1.y, s);
        a1.z += __shfl_down(a1.z, s); a1.w += __shfl_down(a1.w, s);
    }
    int wave = tid >> 6, lane = tid & 63;
    if (lane < 4) { pr0[wave][lane] = a0; pr1[wave][lane] = a1; }
    __syncthreads();
    if (tid < 4) {
        float4 s0 = pr0[0][tid], s1 = pr1[0][tid];
#pragma unroll
        for (int w = 1; w < 4; ++w) {
            s0.x += pr0[w][tid].x; s0.y += pr0[w][tid].y;
            s0.z += pr0[w][tid].z; s0.w += pr0[w][tid].w;
            s1.x += pr1[w][tid].x; s1.y += pr1[w][tid].y;
            s1.z += pr1[w][tid].z; s1.w += pr1[w][tid].w;
        }
        float4 bb = *reinterpret_cast<const float4*>(&b[c0 + tid * 4]);
        s0.x += bb.x; s0.y += bb.y; s0.z += bb.z; s0.w += bb.w;
        s1.x += bb.x; s1.y += bb.y; s1.z += bb.z; s1.w += bb.w;
        *reinterpret_cast<float4*>(&ws[FOFF_Z0 + c0 + tid * 4]) = s0;
        *reinterpret_cast<float4*>(&z1xs[tid * 4]) = s1;   // stays local to block
        __threadfence();
    }

    cooperative_groups::this_grid().sync();

    // ---- Phase 2: full h0/c0 into LDS (each block recomputes; z0 is L2/L3-hot) ----
    {
        int u0 = tid * 4;
        float4 zi = *reinterpret_cast<const float4*>(&ws[FOFF_Z0 + u0]);
        float4 zg = *reinterpret_cast<const float4*>(&ws[FOFF_Z0 + 2 * UNITS + u0]);
        float4 zo = *reinterpret_cast<const float4*>(&ws[FOFF_Z0 + 3 * UNITS + u0]);
        float4 cc, hh;
        cc.x = sigmoidf(zi.x) * zg.x;  hh.x = sigmoidf(zo.x) * cc.x;
        cc.y = sigmoidf(zi.y) * zg.y;  hh.y = sigmoidf(zo.y) * cc.y;
        cc.z = sigmoidf(zi.z) * zg.z;  hh.z = sigmoidf(zo.z) * cc.z;
        cc.w = sigmoidf(zi.w) * zg.w;  hh.w = sigmoidf(zo.w) * cc.w;
        *reinterpret_cast<float4*>(&c0s[u0]) = cc;
        *reinterpret_cast<float4*>(&h0s[u0]) = hh;
    }
    __syncthreads();

    // ---- Phase 3: h0@U from the register tile ----
    float4 a = make_float4(0.f, 0.f, 0.f, 0.f);
#pragma unroll
    for (int it = 0; it < 16; ++it) {
        float h = h0s[it * 64 + rowbase];
        a.x += h * ureg[it].x; a.y += h * ureg[it].y;
        a.z += h * ureg[it].z; a.w += h * ureg[it].w;
    }
#pragma unroll
    for (int s = 32; s >= 4; s >>= 1) {
        a.x += __shfl_down(a.x, s); a.y += __shfl_down(a.y, s);
        a.z += __shfl_down(a.z, s); a.w += __shfl_down(a.w, s);
    }
    if (lane < 4) pr0[wave][lane] = a;
    __syncthreads();
    if (tid < 4) {
        float4 s = pr0[0][tid];
#pragma unroll
        for (int w = 1; w < 4; ++w) {
            s.x += pr0[w][tid].x; s.y += pr0[w][tid].y;
            s.z += pr0[w][tid].z; s.w += pr0[w][tid].w;
        }
        float4 zx = *reinterpret_cast<const float4*>(&z1xs[tid * 4]);
        s.x += zx.x; s.y += zx.y; s.z += zx.z; s.w += zx.w;
        *reinterpret_cast<float4*>(&ws[FOFF_Z1 + c0 + tid * 4]) = s;
        __threadfence();   // release z1 before arrival
    }
    __syncthreads();

    // ---- last-block election (no second grid sync; 255 blocks exit) ----
    if (tid == 0) {
        int prev = __hip_atomic_fetch_add((int*)&ws[FOFF_FLAG], 1,
                                          __ATOMIC_ACQ_REL, __HIP_MEMORY_SCOPE_AGENT);
        lastflag = (prev == (int)gridDim.x - 1) ? 1 : 0;
    }
    __syncthreads();
    if (!lastflag) return;
    __threadfence();       // acquire all blocks' z1 writes

    // ---- Final: step-1 gates, tanh, dense(2), finite-difference outputs ----
    {
        int u0 = tid * 4;
        const float* Z1 = ws + FOFF_Z1;
        float4 zi1 = *reinterpret_cast<const float4*>(&Z1[u0]);
        float4 zf1 = *reinterpret_cast<const float4*>(&Z1[UNITS + u0]);
        float4 zg1 = *reinterpret_cast<const float4*>(&Z1[2 * UNITS + u0]);
        float4 zo1 = *reinterpret_cast<const float4*>(&Z1[3 * UNITS + u0]);
        float4 cc = *reinterpret_cast<const float4*>(&c0s[u0]);   // own LDS copy
        float4 hh = *reinterpret_cast<const float4*>(&h0s[u0]);
        float4 wdA = *reinterpret_cast<const float4*>(&Wd[2 * u0]);      // units u0,u0+1
        float4 wdB = *reinterpret_cast<const float4*>(&Wd[2 * u0 + 4]);  // units u0+2,u0+3
        float4 v = make_float4(0.f, 0.f, 0.f, 0.f);
        float c1, h1, n0, n1;

        c1 = sigmoidf(zf1.x) * cc.x + sigmoidf(zi1.x) * zg1.x;
        h1 = sigmoidf(zo1.x) * c1;
        n0 = tanhf(hh.x); n1 = tanhf(h1);
        v.x += n0 * wdA.x; v.y += n0 * wdA.y; v.z += n1 * wdA.x; v.w += n1 * wdA.y;

        c1 = sigmoidf(zf1.y) * cc.y + sigmoidf(zi1.y) * zg1.y;
        h1 = sigmoidf(zo1.y) * c1;
        n0 = tanhf(hh.y); n1 = tanhf(h1);
        v.x += n0 * wdA.z; v.y += n0 * wdA.w; v.z += n1 * wdA.z; v.w += n1 * wdA.w;

        c1 = sigmoidf(zf1.z) * cc.z + sigmoidf(zi1.z) * zg1.z;
        h1 = sigmoidf(zo1.z) * c1;
        n0 = tanhf(hh.z); n1 = tanhf(h1);
        v.x += n0 * wdB.x; v.y += n0 * wdB.y; v.z += n1 * wdB.x; v.w += n1 * wdB.y;

        c1 = sigmoidf(zf1.w) * cc.w + sigmoidf(zi1.w) * zg1.w;
        h1 = sigmoidf(zo1.w) * c1;
        n0 = tanhf(hh.w); n1 = tanhf(h1);
        v.x += n0 * wdB.z; v.y += n0 * wdB.w; v.z += n1 * wdB.z; v.w += n1 * wdB.w;

#pragma unroll
        for (int s = 32; s > 0; s >>= 1) {
            v.x += __shfl_down(v.x, s);
            v.y += __shfl_down(v.y, s);
            v.z += __shfl_down(v.z, s);
            v.w += __shfl_down(v.w, s);
        }
        if ((tid & 63) == 0) wred[tid >> 6] = v;
        __syncthreads();
        if (tid == 0) {
            float4 sa = wred[0];
#pragma unroll
            for (int w = 1; w < 4; ++w) {
                float4 t = wred[w];
                sa.x += t.x; sa.y += t.y; sa.z += t.z; sa.w += t.w;
            }
            float hc00 = tanhf(sa.x + bd[0]);
            float hc01 = tanhf(sa.y + bd[1]);
            float hc10 = tanhf(sa.z + bd[0]);
            float hc11 = tanhf(sa.w + bd[1]);
            float den = f[1] - f[2];
            out[0] = hc00;
            out[1] = hc01;
            out[2] = (hc00 - hc10) / den;
            out[3] = (hc01 - hc11) / den;
        }
    }
}

// ============================================================================
// Legacy 3-kernel fallback (used only if cooperative launch fails to capture)
// ============================================================================
__global__ __launch_bounds__(256) void k_xw(const float* __restrict__ x,
                                            const float* __restrict__ W,
                                            const float* __restrict__ b,
                                            float* __restrict__ ws) {
    int tid = threadIdx.x;
    int c0 = col_group(blockIdx.x) * 16;

    __shared__ float xs0[FEAT], xs1[FEAT];
    {
        float4 v0 = *reinterpret_cast<const float4*>(&x[tid * 4]);
        float4 v1 = *reinterpret_cast<const float4*>(&x[FEAT + tid * 4]);
        *reinterpret_cast<float4*>(&xs0[tid * 4]) = v0;
        *reinterpret_cast<float4*>(&xs1[tid * 4]) = v1;
    }
    __syncthreads();

    int q = tid & 3;
    int rowbase = tid >> 2;
    const float* wp = W + (size_t)rowbase * GATES + c0 + q * 4;
    float4 a0 = make_float4(0.f, 0.f, 0.f, 0.f);
    float4 a1 = make_float4(0.f, 0.f, 0.f, 0.f);
#pragma unroll
    for (int it = 0; it < 16; ++it) {
        int row = it * 64 + rowbase;
        float4 wv = *reinterpret_cast<const float4*>(wp + (size_t)it * 64 * GATES);
        float x0 = xs0[row], x1 = xs1[row];
        a0.x += x0 * wv.x; a0.y += x0 * wv.y; a0.z += x0 * wv.z; a0.w += x0 * wv.w;
        a1.x += x1 * wv.x; a1.y += x1 * wv.y; a1.z += x1 * wv.z; a1.w += x1 * wv.w;
    }
#pragma unroll
    for (int s = 32; s >= 4; s >>= 1) {
        a0.x += __shfl_down(a0.x, s); a0.y += __shfl_down(a0.y, s);
        a0.z += __shfl_down(a0.z, s); a0.w += __shfl_down(a0.w, s);
        a1.x += __shfl_down(a1.x, s); a1.y += __shfl_down(a1.y, s);
        a1.z += __shfl_down(a1.z, s); a1.w += __shfl_down(a1.w, s);
    }
    __shared__ float4 p0[4][4], p1[4][4];
    int wave = tid >> 6, lane = tid & 63;
    if (lane < 4) { p0[wave][lane] = a0; p1[wave][lane] = a1; }
    __syncthreads();
    if (tid < 4) {
        float4 s0 = p0[0][tid], s1 = p1[0][tid];
#pragma unroll
        for (int w = 1; w < 4; ++w) {
            s0.x += p0[w][tid].x; s0.y += p0[w][tid].y; s0.z += p0[w][tid].z; s0.w += p0[w][tid].w;
            s1.x += p1[w][tid].x; s1.y += p1[w][tid].y; s1.z += p1[w][tid].z; s1.w += p1[w][tid].w;
        }
        float4 bb = *reinterpret_cast<const float4*>(&b[c0 + tid * 4]);
        s0.x += bb.x; s0.y += bb.y; s0.z += bb.z; s0.w += bb.w;
        s1.x += bb.x; s1.y += bb.y; s1.z += bb.z; s1.w += bb.w;
        *reinterpret_cast<float4*>(&ws[OFF_Z0 + c0 + tid * 4]) = s0;
        *reinterpret_cast<float4*>(&ws[OFF_Z1X + c0 + tid * 4]) = s1;
    }
}

__global__ __launch_bounds__(256) void k_hu(const float* __restrict__ U,
                                            float* __restrict__ ws) {
    int tid = threadIdx.x;
    int c0 = col_group(blockIdx.x) * 16;

    __shared__ float h0s[UNITS];
    {
        int u0 = tid * 4;
        float4 zi = *reinterpret_cast<const float4*>(&ws[OFF_Z0 + u0]);
        float4 zg = *reinterpret_cast<const float4*>(&ws[OFF_Z0 + 2 * UNITS + u0]);
        float4 zo = *reinterpret_cast<const float4*>(&ws[OFF_Z0 + 3 * UNITS + u0]);
        float4 h;
        h.x = sigmoidf(zo.x) * (sigmoidf(zi.x) * zg.x);
        h.y = sigmoidf(zo.y) * (sigmoidf(zi.y) * zg.y);
        h.z = sigmoidf(zo.z) * (sigmoidf(zi.z) * zg.z);
        h.w = sigmoidf(zo.w) * (sigmoidf(zi.w) * zg.w);
        *reinterpret_cast<float4*>(&h0s[u0]) = h;
    }
    __syncthreads();

    int q = tid & 3;
    int rowbase = tid >> 2;
    const float* up = U + (size_t)rowbase * GATES + c0 + q * 4;
    float4 a = make_float4(0.f, 0.f, 0.f, 0.f);
#pragma unroll
    for (int it = 0; it < 16; ++it) {
        int row = it * 64 + rowbase;
        float4 u4 = *reinterpret_cast<const float4*>(up + (size_t)it * 64 * GATES);
        float h = h0s[row];
        a.x += h * u4.x; a.y += h * u4.y; a.z += h * u4.z; a.w += h * u4.w;
    }
#pragma unroll
    for (int s = 32; s >= 4; s >>= 1) {
        a.x += __shfl_down(a.x, s); a.y += __shfl_down(a.y, s);
        a.z += __shfl_down(a.z, s); a.w += __shfl_down(a.w, s);
    }
    __shared__ float4 pu[4][4];
    int wave = tid >> 6, lane = tid & 63;
    if (lane < 4) pu[wave][lane] = a;
    __syncthreads();
    if (tid < 4) {
        float4 s = pu[0][tid];
#pragma unroll
        for (int w = 1; w < 4; ++w) {
            s.x += pu[w][tid].x; s.y += pu[w][tid].y; s.z += pu[w][tid].z; s.w += pu[w][tid].w;
        }
        float4 zx = *reinterpret_cast<const float4*>(&ws[OFF_Z1X + c0 + tid * 4]);
        s.x += zx.x; s.y += zx.y; s.z += zx.z; s.w += zx.w;
        *reinterpret_cast<float4*>(&ws[OFF_Z1L + c0 + tid * 4]) = s;
    }
}

__global__ __launch_bounds__(1024) void k_final(const float* __restrict__ ws,
                                                const float* __restrict__ f,
                                                const float* __restrict__ Wd,
                                                const float* __restrict__ bd,
                                                float* __restrict__ out) {
    int u = threadIdx.x;
    const float* Z0 = ws + OFF_Z0;
    const float* Z1 = ws + OFF_Z1L;
    float c0 = sigmoidf(Z0[u]) * Z0[u + 2 * UNITS];
    float h0 = sigmoidf(Z0[u + 3 * UNITS]) * c0;
    float c1 = sigmoidf(Z1[u + UNITS]) * c0 + sigmoidf(Z1[u]) * Z1[u + 2 * UNITS];
    float h1 = sigmoidf(Z1[u + 3 * UNITS]) * c1;

    float n0 = tanhf(h0);
    float n1 = tanhf(h1);
    float2 wd = *reinterpret_cast<const float2*>(&Wd[2 * u]);

    float4 v = make_float4(n0 * wd.x, n0 * wd.y, n1 * wd.x, n1 * wd.y);
#pragma unroll
    for (int s = 32; s > 0; s >>= 1) {
        v.x += __shfl_down(v.x, s);
        v.y += __shfl_down(v.y, s);
        v.z += __shfl_down(v.z, s);
        v.w += __shfl_down(v.w, s);
    }
    __shared__ float4 wred[16];
    int wave = u >> 6;
    if ((u & 63) == 0) wred[wave] = v;
    __syncthreads();
    if (u == 0) {
        float4 sa = wred[0];
#pragma unroll
        for (int w = 1; w < 16; ++w) {
            float4 t = wred[w];
            sa.x += t.x; sa.y += t.y; sa.z += t.z; sa.w += t.w;
        }
        float hc00 = tanhf(sa.x + bd[0]);
        float hc01 = tanhf(sa.y + bd[1]);
        float hc10 = tanhf(sa.z + bd[0]);
        float hc11 = tanhf(sa.w + bd[1]);
        float den = f[1] - f[2];
        out[0] = hc00;
        out[1] = hc01;
        out[2] = (hc00 - hc10) / den;
        out[3] = (hc01 - hc11) / den;
    }
}

extern "C" void kernel_launch(void* const* d_in, const int* in_sizes, int n_in,
                              void* d_out, int out_size, void* d_ws, size_t ws_size,
                              hipStream_t stream) {
    const float* x  = (const float*)d_in[0];  // (1, 8192, 1024) — only rows 0,1 used
    const float* f  = (const float*)d_in[1];  // (8192, 1)
    const float* W  = (const float*)d_in[2];  // (1024, 4096)
    const float* U  = (const float*)d_in[3];  // (1024, 4096)
    const float* b  = (const float*)d_in[4];  // (4096,)
    const float* Wd = (const float*)d_in[5];  // (1024, 2)
    const float* bd = (const float*)d_in[6];  // (2,)
    float* out = (float*)d_out;               // 4 floats
    float* ws  = (float*)d_ws;                // 33 KB scratch used

    void* args[] = {(void*)&x, (void*)&W, (void*)&U, (void*)&b,
                    (void*)&f, (void*)&Wd, (void*)&bd, (void*)&ws, (void*)&out};
    hipError_t err = hipLaunchCooperativeKernel(
        reinterpret_cast<const void*>(&k_fused), dim3(256), dim3(256), args, 0, stream);
    if (err != hipSuccess) {
        // graph-capture of cooperative launch unsupported → legacy 3-kernel path
        (void)hipGetLastError();
        k_xw   <<<256, 256, 0, stream>>>(x, W, b, ws);
        k_hu   <<<256, 256, 0, stream>>>(U, ws);
        k_final<<<  1, 1024, 0, stream>>>(ws, f, Wd, bd, out);
    }
}

// Round 2
// 128.559 us; speedup vs baseline: 1.3525x; 1.3525x over previous
//
#include <hip/hip_runtime.h>
#include <math.h>

#define UNITS 1024
#define FEAT  1024
#define GATES 4096   // 4*UNITS

// ws layout (float offsets)
#define OFF_Z0  0            // z0  = b + x0@W   (4096)
#define OFF_Z1X (GATES)      // z1x = b + x1@W   (4096)
#define OFF_Z1  (2*GATES)    // z1  = z1x + h0@U (4096)

// Cross-iteration flags live in device globals (zero-init at load; each
// launch ends with them reset to 0 by the final block). NOT in ws — ws is
// poisoned between iterations.
__device__ int g_w_done = 0;
__device__ int g_u_done = 0;

__device__ __forceinline__ float sigmoidf(float x) { return 1.0f / (1.0f + expf(-x)); }

// XCD-aware swizzle (bx%8 = XCD heuristic): each XCD owns 32 consecutive
// 16-col groups = 512 contiguous columns.
__device__ __forceinline__ int col_group(int bx) {
    return ((bx & 7) << 5) + (bx >> 3);
}

// ============================================================================
// Single plain-launch kernel, 512 blocks x 256 threads, 2 blocks/CU
// (resource-guaranteed co-residency: ~9 KB LDS, VGPR <= 256 via launch_bounds).
//
// Blocks 0..255   (W half): z0 = b + x0@W, z1x = b + x1@W -> ws, then one
//                           RELEASE fetch_add on g_w_done. No spinning.
// Blocks 256..511 (U half): prefetch 64 KB U tile into registers (keep-alive
//                           asm pins it — HBM read overlaps the W half), then
//                           RELAXED-poll g_w_done==256 (sc1 load, no L2
//                           invalidate per poll), one ACQUIRE at exit,
//                           recompute h0/c0 from z0, z1 = z1x + h0@U -> ws.
// Last U-arriver: step-1 gates + tanh + dense(2) + finite-diff outputs,
//                 then resets both flags for the next graph replay.
// ============================================================================
__global__ __launch_bounds__(256, 2) void k_lstm(
        const float* __restrict__ x,
        const float* __restrict__ W,
        const float* __restrict__ U,
        const float* __restrict__ b,
        const float* __restrict__ f,
        const float* __restrict__ Wd,
        const float* __restrict__ bd,
        float* __restrict__ ws,
        float* __restrict__ out) {
    int tid = threadIdx.x;
    int wave = tid >> 6, lane = tid & 63;
    int q = tid & 3, rowbase = tid >> 2;        // rowbase 0..63

    __shared__ float sm[2048];                   // W half: xs0|xs1; U half: h0s|c0s
    __shared__ float4 pr0[4][4], pr1[4][4];
    __shared__ float4 wred[4];
    __shared__ int lastflag;

    if (blockIdx.x < 256) {
        // ------------------------------ W half ------------------------------
        int c0 = col_group(blockIdx.x) * 16;
        {
            float4 v0 = *reinterpret_cast<const float4*>(&x[tid * 4]);
            float4 v1 = *reinterpret_cast<const float4*>(&x[FEAT + tid * 4]);
            *reinterpret_cast<float4*>(&sm[tid * 4]) = v0;          // xs0
            *reinterpret_cast<float4*>(&sm[FEAT + tid * 4]) = v1;   // xs1
        }
        __syncthreads();

        const float* wp = W + (size_t)rowbase * GATES + c0 + q * 4;
        float4 a0 = make_float4(0.f, 0.f, 0.f, 0.f);
        float4 a1 = make_float4(0.f, 0.f, 0.f, 0.f);
#pragma unroll
        for (int it = 0; it < 16; ++it) {
            int row = it * 64 + rowbase;
            float4 wv = *reinterpret_cast<const float4*>(wp + (size_t)it * 64 * GATES);
            float x0 = sm[row], x1 = sm[FEAT + row];
            a0.x += x0 * wv.x; a0.y += x0 * wv.y; a0.z += x0 * wv.z; a0.w += x0 * wv.w;
            a1.x += x1 * wv.x; a1.y += x1 * wv.y; a1.z += x1 * wv.z; a1.w += x1 * wv.w;
        }
#pragma unroll
        for (int s = 32; s >= 4; s >>= 1) {
            a0.x += __shfl_down(a0.x, s); a0.y += __shfl_down(a0.y, s);
            a0.z += __shfl_down(a0.z, s); a0.w += __shfl_down(a0.w, s);
            a1.x += __shfl_down(a1.x, s); a1.y += __shfl_down(a1.y, s);
            a1.z += __shfl_down(a1.z, s); a1.w += __shfl_down(a1.w, s);
        }
        if (lane < 4) { pr0[wave][lane] = a0; pr1[wave][lane] = a1; }
        __syncthreads();
        if (tid < 4) {
            float4 s0 = pr0[0][tid], s1 = pr1[0][tid];
#pragma unroll
            for (int w = 1; w < 4; ++w) {
                s0.x += pr0[w][tid].x; s0.y += pr0[w][tid].y;
                s0.z += pr0[w][tid].z; s0.w += pr0[w][tid].w;
                s1.x += pr1[w][tid].x; s1.y += pr1[w][tid].y;
                s1.z += pr1[w][tid].z; s1.w += pr1[w][tid].w;
            }
            float4 bb = *reinterpret_cast<const float4*>(&b[c0 + tid * 4]);
            s0.x += bb.x; s0.y += bb.y; s0.z += bb.z; s0.w += bb.w;
            s1.x += bb.x; s1.y += bb.y; s1.z += bb.z; s1.w += bb.w;
            *reinterpret_cast<float4*>(&ws[OFF_Z0 + c0 + tid * 4]) = s0;
            *reinterpret_cast<float4*>(&ws[OFF_Z1X + c0 + tid * 4]) = s1;
        }
        __syncthreads();   // all block stores complete (per-wave vmcnt drained)
        if (tid == 0) {
            // RELEASE at agent scope: writes back this XCD's L2 once, then
            // publishes arrival at the device coherence point.
            __hip_atomic_fetch_add(&g_w_done, 1, __ATOMIC_RELEASE,
                                   __HIP_MEMORY_SCOPE_AGENT);
        }
        return;
    }

    // -------------------------------- U half --------------------------------
    int c0 = col_group(blockIdx.x - 256) * 16;
    const float* up = U + (size_t)rowbase * GATES + c0 + q * 4;

    // Prefetch U tile into registers; pin with asm so the loads cannot be
    // sunk below the spin (round-1 failure mode: VGPR_Count=64 proved sink).
    float4 ureg[16];
#pragma unroll
    for (int it = 0; it < 16; ++it)
        ureg[it] = *reinterpret_cast<const float4*>(up + (size_t)it * 64 * GATES);
#pragma unroll
    for (int it = 0; it < 16; ++it)
        asm volatile("" : "+v"(ureg[it].x), "+v"(ureg[it].y),
                          "+v"(ureg[it].z), "+v"(ureg[it].w));

    if (tid == 0) {
        // Relaxed agent-scope poll: sc1 load, sees remote updates without a
        // per-poll cache invalidate. Single ACQUIRE once the flag is up.
        while (__hip_atomic_load(&g_w_done, __ATOMIC_RELAXED,
                                 __HIP_MEMORY_SCOPE_AGENT) < 256)
            __builtin_amdgcn_s_sleep(2);
        (void)__hip_atomic_load(&g_w_done, __ATOMIC_ACQUIRE,
                                __HIP_MEMORY_SCOPE_AGENT);
    }
    __syncthreads();

    // h0/c0 for ALL 1024 units from z0 (16 KB from L3; identical math to k_hu)
    {
        int u0 = tid * 4;
        float4 zi = *reinterpret_cast<const float4*>(&ws[OFF_Z0 + u0]);
        float4 zg = *reinterpret_cast<const float4*>(&ws[OFF_Z0 + 2 * UNITS + u0]);
        float4 zo = *reinterpret_cast<const float4*>(&ws[OFF_Z0 + 3 * UNITS + u0]);
        float4 cc, hh;
        cc.x = sigmoidf(zi.x) * zg.x;  hh.x = sigmoidf(zo.x) * cc.x;
        cc.y = sigmoidf(zi.y) * zg.y;  hh.y = sigmoidf(zo.y) * cc.y;
        cc.z = sigmoidf(zi.z) * zg.z;  hh.z = sigmoidf(zo.z) * cc.z;
        cc.w = sigmoidf(zi.w) * zg.w;  hh.w = sigmoidf(zo.w) * cc.w;
        *reinterpret_cast<float4*>(&sm[u0]) = hh;            // h0s
        *reinterpret_cast<float4*>(&sm[UNITS + u0]) = cc;    // c0s
    }
    __syncthreads();

    // z1 = z1x + h0@U from the register tile
    float4 a = make_float4(0.f, 0.f, 0.f, 0.f);
#pragma unroll
    for (int it = 0; it < 16; ++it) {
        float h = sm[it * 64 + rowbase];
        a.x += h * ureg[it].x; a.y += h * ureg[it].y;
        a.z += h * ureg[it].z; a.w += h * ureg[it].w;
    }
#pragma unroll
    for (int s = 32; s >= 4; s >>= 1) {
        a.x += __shfl_down(a.x, s); a.y += __shfl_down(a.y, s);
        a.z += __shfl_down(a.z, s); a.w += __shfl_down(a.w, s);
    }
    if (lane < 4) pr0[wave][lane] = a;
    __syncthreads();
    if (tid < 4) {
        float4 s = pr0[0][tid];
#pragma unroll
        for (int w = 1; w < 4; ++w) {
            s.x += pr0[w][tid].x; s.y += pr0[w][tid].y;
            s.z += pr0[w][tid].z; s.w += pr0[w][tid].w;
        }
        float4 zx = *reinterpret_cast<const float4*>(&ws[OFF_Z1X + c0 + tid * 4]);
        s.x += zx.x; s.y += zx.y; s.z += zx.z; s.w += zx.w;
        *reinterpret_cast<float4*>(&ws[OFF_Z1 + c0 + tid * 4]) = s;
    }
    __syncthreads();   // z1 stores complete before the release add

    // Last-arriver election among U blocks (one-shot, no spinning).
    if (tid == 0) {
        int prev = __hip_atomic_fetch_add(&g_u_done, 1, __ATOMIC_ACQ_REL,
                                          __HIP_MEMORY_SCOPE_AGENT);
        lastflag = (prev == 255) ? 1 : 0;
    }
    __syncthreads();
    if (!lastflag) return;

    // ---- Finale (round-1-verified numerics): step-1 gates, tanh, dense(2) ----
    {
        int u0 = tid * 4;
        const float* Z1 = ws + OFF_Z1;
        float4 zi1 = *reinterpret_cast<const float4*>(&Z1[u0]);
        float4 zf1 = *reinterpret_cast<const float4*>(&Z1[UNITS + u0]);
        float4 zg1 = *reinterpret_cast<const float4*>(&Z1[2 * UNITS + u0]);
        float4 zo1 = *reinterpret_cast<const float4*>(&Z1[3 * UNITS + u0]);
        float4 hh = *reinterpret_cast<const float4*>(&sm[u0]);           // h0
        float4 cc = *reinterpret_cast<const float4*>(&sm[UNITS + u0]);   // c0
        float4 wdA = *reinterpret_cast<const float4*>(&Wd[2 * u0]);      // units u0,u0+1
        float4 wdB = *reinterpret_cast<const float4*>(&Wd[2 * u0 + 4]);  // units u0+2,u0+3
        float4 v = make_float4(0.f, 0.f, 0.f, 0.f);
        float c1, h1, n0, n1;

        c1 = sigmoidf(zf1.x) * cc.x + sigmoidf(zi1.x) * zg1.x;
        h1 = sigmoidf(zo1.x) * c1;
        n0 = tanhf(hh.x); n1 = tanhf(h1);
        v.x += n0 * wdA.x; v.y += n0 * wdA.y; v.z += n1 * wdA.x; v.w += n1 * wdA.y;

        c1 = sigmoidf(zf1.y) * cc.y + sigmoidf(zi1.y) * zg1.y;
        h1 = sigmoidf(zo1.y) * c1;
        n0 = tanhf(hh.y); n1 = tanhf(h1);
        v.x += n0 * wdA.z; v.y += n0 * wdA.w; v.z += n1 * wdA.z; v.w += n1 * wdA.w;

        c1 = sigmoidf(zf1.z) * cc.z + sigmoidf(zi1.z) * zg1.z;
        h1 = sigmoidf(zo1.z) * c1;
        n0 = tanhf(hh.z); n1 = tanhf(h1);
        v.x += n0 * wdB.x; v.y += n0 * wdB.y; v.z += n1 * wdB.x; v.w += n1 * wdB.y;

        c1 = sigmoidf(zf1.w) * cc.w + sigmoidf(zi1.w) * zg1.w;
        h1 = sigmoidf(zo1.w) * c1;
        n0 = tanhf(hh.w); n1 = tanhf(h1);
        v.x += n0 * wdB.z; v.y += n0 * wdB.w; v.z += n1 * wdB.z; v.w += n1 * wdB.w;

#pragma unroll
        for (int s = 32; s > 0; s >>= 1) {
            v.x += __shfl_down(v.x, s);
            v.y += __shfl_down(v.y, s);
            v.z += __shfl_down(v.z, s);
            v.w += __shfl_down(v.w, s);
        }
        if ((tid & 63) == 0) wred[tid >> 6] = v;
        __syncthreads();
        if (tid == 0) {
            float4 sa = wred[0];
#pragma unroll
            for (int w = 1; w < 4; ++w) {
                float4 t = wred[w];
                sa.x += t.x; sa.y += t.y; sa.z += t.z; sa.w += t.w;
            }
            float hc00 = tanhf(sa.x + bd[0]);
            float hc01 = tanhf(sa.y + bd[1]);
            float hc10 = tanhf(sa.z + bd[0]);
            float hc11 = tanhf(sa.w + bd[1]);
            float den = f[1] - f[2];
            out[0] = hc00;
            out[1] = hc01;
            out[2] = (hc00 - hc10) / den;
            out[3] = (hc01 - hc11) / den;

            // Reset flags for the next graph replay (all spins already exited:
            // every U-block's fetch_add preceded this block's election).
            __hip_atomic_store(&g_w_done, 0, __ATOMIC_RELAXED,
                               __HIP_MEMORY_SCOPE_AGENT);
            __hip_atomic_store(&g_u_done, 0, __ATOMIC_RELAXED,
                               __HIP_MEMORY_SCOPE_AGENT);
        }
    }
}

extern "C" void kernel_launch(void* const* d_in, const int* in_sizes, int n_in,
                              void* d_out, int out_size, void* d_ws, size_t ws_size,
                              hipStream_t stream) {
    const float* x  = (const float*)d_in[0];  // (1, 8192, 1024) — only rows 0,1 used
    const float* f  = (const float*)d_in[1];  // (8192, 1)
    const float* W  = (const float*)d_in[2];  // (1024, 4096)
    const float* U  = (const float*)d_in[3];  // (1024, 4096)
    const float* b  = (const float*)d_in[4];  // (4096,)
    const float* Wd = (const float*)d_in[5];  // (1024, 2)
    const float* bd = (const float*)d_in[6];  // (2,)
    float* out = (float*)d_out;               // 4 floats
    float* ws  = (float*)d_ws;                // 48 KB scratch used

    k_lstm<<<512, 256, 0, stream>>>(x, W, U, b, f, Wd, bd, ws, out);
}

// Round 3
// 105.679 us; speedup vs baseline: 1.6453x; 1.2165x over previous
//
#include <hip/hip_runtime.h>
#include <math.h>

#define UNITS 1024
#define FEAT  1024
#define GATES 4096   // 4*UNITS

// ws layout (float offsets) — no partials, just the three 4096-vectors
#define OFF_Z0  0                 // z0  = b + x0@W
#define OFF_Z1X (GATES)           // z1x = b + x1@W
#define OFF_Z1  (2*GATES)         // z1  = z1x + h0@U

__device__ __forceinline__ float sigmoidf(float x) { return 1.0f / (1.0f + expf(-x)); }

// Column-group for a block: XCD-aware swizzle (bx%8 = XCD heuristic) so each
// XCD owns 32 consecutive 16-col groups = 512 contiguous columns.
__device__ __forceinline__ int col_group(int bx) {
    return ((bx & 7) << 5) + (bx >> 3);
}

// K1: 256 blocks, each computes 16 full-depth columns of BOTH x0@W and x1@W,
// writing z0 and z1x directly. W read exactly once, no partials, no atomics.
// ALSO: prefetches this block's U tile (same col_group -> same XCD) into
// L2/L3 using the HBM bandwidth left idle by the dependent W-FMA phase, so
// K2's U read is cache-hot. Keep-alive asm pins the loads (otherwise DCE'd).
__global__ __launch_bounds__(256) void k_xw(const float* __restrict__ x,
                                            const float* __restrict__ W,
                                            const float* __restrict__ U,
                                            const float* __restrict__ b,
                                            float* __restrict__ ws) {
    int tid = threadIdx.x;
    int c0 = col_group(blockIdx.x) * 16;

    __shared__ float xs0[FEAT], xs1[FEAT];
    {
        float4 v0 = *reinterpret_cast<const float4*>(&x[tid * 4]);
        float4 v1 = *reinterpret_cast<const float4*>(&x[FEAT + tid * 4]);
        *reinterpret_cast<float4*>(&xs0[tid * 4]) = v0;
        *reinterpret_cast<float4*>(&xs1[tid * 4]) = v1;
    }
    __syncthreads();

    int q = tid & 3;
    int rowbase = tid >> 2;           // 0..63
    const float* wp = W + (size_t)rowbase * GATES + c0 + q * 4;
    const float* up = U + (size_t)rowbase * GATES + c0 + q * 4;
    float4 a0 = make_float4(0.f, 0.f, 0.f, 0.f);
    float4 a1 = make_float4(0.f, 0.f, 0.f, 0.f);
#pragma unroll
    for (int it = 0; it < 16; ++it) {
        int row = it * 64 + rowbase;
        float4 w = *reinterpret_cast<const float4*>(wp + (size_t)it * 64 * GATES);
        float x0 = xs0[row], x1 = xs1[row];
        a0.x += x0 * w.x; a0.y += x0 * w.y; a0.z += x0 * w.z; a0.w += x0 * w.w;
        a1.x += x1 * w.x; a1.y += x1 * w.y; a1.z += x1 * w.z; a1.w += x1 * w.w;
    }

    // U-tile prefetch: issued AFTER the W loads (vmcnt completion is in-order;
    // issuing U first would stall every W consumer behind all 16 U returns).
    // Exact same addresses K2 will read -> warms the right lines, same XCD.
    float4 ureg[16];
#pragma unroll
    for (int it = 0; it < 16; ++it)
        ureg[it] = *reinterpret_cast<const float4*>(up + (size_t)it * 64 * GATES);

    // reduce across rowbase (stride-4 lanes share q)
#pragma unroll
    for (int s = 32; s >= 4; s >>= 1) {
        a0.x += __shfl_down(a0.x, s); a0.y += __shfl_down(a0.y, s);
        a0.z += __shfl_down(a0.z, s); a0.w += __shfl_down(a0.w, s);
        a1.x += __shfl_down(a1.x, s); a1.y += __shfl_down(a1.y, s);
        a1.z += __shfl_down(a1.z, s); a1.w += __shfl_down(a1.w, s);
    }
    __shared__ float4 p0[4][4], p1[4][4];   // [wave][q]
    int wave = tid >> 6, lane = tid & 63;
    if (lane < 4) { p0[wave][lane] = a0; p1[wave][lane] = a1; }
    __syncthreads();
    if (tid < 4) {
        float4 s0 = p0[0][tid], s1 = p1[0][tid];
#pragma unroll
        for (int w = 1; w < 4; ++w) {
            s0.x += p0[w][tid].x; s0.y += p0[w][tid].y; s0.z += p0[w][tid].z; s0.w += p0[w][tid].w;
            s1.x += p1[w][tid].x; s1.y += p1[w][tid].y; s1.z += p1[w][tid].z; s1.w += p1[w][tid].w;
        }
        float4 bb = *reinterpret_cast<const float4*>(&b[c0 + tid * 4]);
        s0.x += bb.x; s0.y += bb.y; s0.z += bb.z; s0.w += bb.w;
        s1.x += bb.x; s1.y += bb.y; s1.z += bb.z; s1.w += bb.w;
        *reinterpret_cast<float4*>(&ws[OFF_Z0 + c0 + tid * 4]) = s0;
        *reinterpret_cast<float4*>(&ws[OFF_Z1X + c0 + tid * 4]) = s1;
    }

    // Keep-alive: forces the 16 U loads to exist and complete (cache fill).
    // Placed last so the drain overlaps the reduce/store phase, not the FMAs.
#pragma unroll
    for (int it = 0; it < 16; ++it)
        asm volatile("" :: "v"(ureg[it].x), "v"(ureg[it].y),
                           "v"(ureg[it].z), "v"(ureg[it].w));
}

// K2: 256 blocks, each recomputes all 1024 h0 from z0 (12 KB, L2-hot) into LDS,
// then computes 16 full-depth columns of h0@U (U now L2/L3-hot from K1's
// prefetch) and writes z1 = z1x + that.
__global__ __launch_bounds__(256) void k_hu(const float* __restrict__ U,
                                            float* __restrict__ ws) {
    int tid = threadIdx.x;
    int c0 = col_group(blockIdx.x) * 16;

    __shared__ float h0s[UNITS];
    {
        int u0 = tid * 4;
        float4 zi = *reinterpret_cast<const float4*>(&ws[OFF_Z0 + u0]);
        float4 zg = *reinterpret_cast<const float4*>(&ws[OFF_Z0 + 2 * UNITS + u0]);
        float4 zo = *reinterpret_cast<const float4*>(&ws[OFF_Z0 + 3 * UNITS + u0]);
        float4 h;
        h.x = sigmoidf(zo.x) * (sigmoidf(zi.x) * zg.x);
        h.y = sigmoidf(zo.y) * (sigmoidf(zi.y) * zg.y);
        h.z = sigmoidf(zo.z) * (sigmoidf(zi.z) * zg.z);
        h.w = sigmoidf(zo.w) * (sigmoidf(zi.w) * zg.w);
        *reinterpret_cast<float4*>(&h0s[u0]) = h;
    }
    __syncthreads();

    int q = tid & 3;
    int rowbase = tid >> 2;
    const float* up = U + (size_t)rowbase * GATES + c0 + q * 4;
    float4 a = make_float4(0.f, 0.f, 0.f, 0.f);
#pragma unroll
    for (int it = 0; it < 16; ++it) {
        int row = it * 64 + rowbase;
        float4 u4 = *reinterpret_cast<const float4*>(up + (size_t)it * 64 * GATES);
        float h = h0s[row];
        a.x += h * u4.x; a.y += h * u4.y; a.z += h * u4.z; a.w += h * u4.w;
    }
#pragma unroll
    for (int s = 32; s >= 4; s >>= 1) {
        a.x += __shfl_down(a.x, s); a.y += __shfl_down(a.y, s);
        a.z += __shfl_down(a.z, s); a.w += __shfl_down(a.w, s);
    }
    __shared__ float4 pu[4][4];
    int wave = tid >> 6, lane = tid & 63;
    if (lane < 4) pu[wave][lane] = a;
    __syncthreads();
    if (tid < 4) {
        float4 s = pu[0][tid];
#pragma unroll
        for (int w = 1; w < 4; ++w) {
            s.x += pu[w][tid].x; s.y += pu[w][tid].y; s.z += pu[w][tid].z; s.w += pu[w][tid].w;
        }
        float4 zx = *reinterpret_cast<const float4*>(&ws[OFF_Z1X + c0 + tid * 4]);
        s.x += zx.x; s.y += zx.y; s.z += zx.z; s.w += zx.w;
        *reinterpret_cast<float4*>(&ws[OFF_Z1 + c0 + tid * 4]) = s;
    }
}

// K3: gates for steps 0/1, tanh, dense(2) reduction, outputs. 1 block x 1024.
__global__ __launch_bounds__(1024) void k_final(const float* __restrict__ ws,
                                                const float* __restrict__ f,
                                                const float* __restrict__ Wd,
                                                const float* __restrict__ bd,
                                                float* __restrict__ out) {
    int u = threadIdx.x;  // 0..1023
    const float* Z0 = ws + OFF_Z0;
    const float* Z1 = ws + OFF_Z1;
    float c0 = sigmoidf(Z0[u]) * Z0[u + 2 * UNITS];
    float h0 = sigmoidf(Z0[u + 3 * UNITS]) * c0;
    float c1 = sigmoidf(Z1[u + UNITS]) * c0 + sigmoidf(Z1[u]) * Z1[u + 2 * UNITS];
    float h1 = sigmoidf(Z1[u + 3 * UNITS]) * c1;

    float n0 = tanhf(h0);
    float n1 = tanhf(h1);
    float2 wd = *reinterpret_cast<const float2*>(&Wd[2 * u]);

    float4 v = make_float4(n0 * wd.x, n0 * wd.y, n1 * wd.x, n1 * wd.y);
#pragma unroll
    for (int s = 32; s > 0; s >>= 1) {
        v.x += __shfl_down(v.x, s);
        v.y += __shfl_down(v.y, s);
        v.z += __shfl_down(v.z, s);
        v.w += __shfl_down(v.w, s);
    }
    __shared__ float4 wred[16];
    int wave = u >> 6;
    if ((u & 63) == 0) wred[wave] = v;
    __syncthreads();
    if (u == 0) {
        float4 sa = wred[0];
#pragma unroll
        for (int w = 1; w < 16; ++w) {
            float4 t = wred[w];
            sa.x += t.x; sa.y += t.y; sa.z += t.z; sa.w += t.w;
        }
        float hc00 = tanhf(sa.x + bd[0]);
        float hc01 = tanhf(sa.y + bd[1]);
        float hc10 = tanhf(sa.z + bd[0]);
        float hc11 = tanhf(sa.w + bd[1]);
        float den = f[1] - f[2];
        out[0] = hc00;
        out[1] = hc01;
        out[2] = (hc00 - hc10) / den;
        out[3] = (hc01 - hc11) / den;
    }
}

extern "C" void kernel_launch(void* const* d_in, const int* in_sizes, int n_in,
                              void* d_out, int out_size, void* d_ws, size_t ws_size,
                              hipStream_t stream) {
    const float* x  = (const float*)d_in[0];  // (1, 8192, 1024) — only rows 0,1 used
    const float* f  = (const float*)d_in[1];  // (8192, 1)
    const float* W  = (const float*)d_in[2];  // (1024, 4096)
    const float* U  = (const float*)d_in[3];  // (1024, 4096)
    const float* b  = (const float*)d_in[4];  // (4096,)
    const float* Wd = (const float*)d_in[5];  // (1024, 2)
    const float* bd = (const float*)d_in[6];  // (2,)
    float* out = (float*)d_out;               // 4 floats
    float* ws  = (float*)d_ws;                // 48 KB scratch used

    k_xw   <<<256, 256, 0, stream>>>(x, W, U, b, ws);
    k_hu   <<<256, 256, 0, stream>>>(U, ws);
    k_final<<<  1, 1024, 0, stream>>>(ws, f, Wd, bd, out);
}